// Round 14
// baseline (188.440 us; speedup 1.0000x reference)
//
#include <hip/hip_runtime.h>
#include <hip/hip_bf16.h>

#define N_NODES 50000
#define K_EIG   512
#define F_DIM   128
#define NPAD    51200     // 200 wave-splits * 256
#define NWSPL   200       // wave-level splits
#define NT32    1600      // NPAD/32

typedef __attribute__((ext_vector_type(8))) short bf16x8;
typedef __attribute__((ext_vector_type(4))) short s16x4;
typedef __attribute__((ext_vector_type(4))) float f32x4;
typedef __attribute__((ext_vector_type(2))) unsigned u32x2;

static __device__ __forceinline__ unsigned pk2(float lo, float hi) {
    unsigned short a = __builtin_bit_cast(unsigned short, __float2bfloat16(lo));
    unsigned short b = __builtin_bit_cast(unsigned short, __float2bfloat16(hi));
    return ((unsigned)b << 16) | (unsigned)a;
}

static __device__ __forceinline__ short f2bf(float f) {
    union { float f; unsigned u; } v; v.f = f;
    unsigned r = v.u + 0x7fffu + ((v.u >> 16) & 1u);   // RNE
    return (short)(r >> 16);
}

static __device__ __forceinline__ float bf2f(unsigned short u) {
    union { unsigned u; float f; } v; v.u = ((unsigned)u) << 16;
    return v.f;
}

// ---------------- prep: x -> xTa fragment-ready ------------------------------
// xTa[ft16(8)][nt32(1600)][lane(64)][8]: xTa[ft][nt][16h+m][j] = x[nt*32+8h+j][ft*16+m]
__global__ __launch_bounds__(256) void prep_x(const float* __restrict__ x,
                                              unsigned short* __restrict__ xTa)
{
    const int n0 = blockIdx.x * 64;
    const int f0 = blockIdx.y * 64;
    const int fa = threadIdx.x & 15;
    const int nb = threadIdx.x >> 4;
    const int n  = n0 + 4 * nb;
    const int f  = f0 + 4 * fa;

    float r[4][4];
    #pragma unroll
    for (int jj = 0; jj < 4; ++jj) {
        int nr = n + jj;
        if (nr < N_NODES) {
            f32x4 v = *reinterpret_cast<const f32x4*>(x + (long)nr * F_DIM + f);
            r[jj][0] = v[0]; r[jj][1] = v[1]; r[jj][2] = v[2]; r[jj][3] = v[3];
        } else {
            r[jj][0] = r[jj][1] = r[jj][2] = r[jj][3] = 0.f;
        }
    }
    const int nt32 = n >> 5;
    const int hpart = ((n >> 3) & 3) * 16;
    const int slot  = 4 * (nb & 1);
    #pragma unroll
    for (int i = 0; i < 4; ++i) {
        int fi = f + i;
        size_t ad = ((size_t)((fi >> 4) * NT32 + nt32) * 64 + hpart + (fi & 15)) * 8 + slot;
        u32x2 w; w[0] = pk2(r[0][i], r[1][i]); w[1] = pk2(r[2][i], r[3][i]);
        *reinterpret_cast<u32x2*>(xTa + ad) = w;
    }
}

// ---------------- GEMM1 fused: A-frags straight from f32 U -------------------
// grid (8 ktB, 100); 4 waves = (n-half) x (f-half). Wave: 256n x 64k x 64f.
// part2[((ktB*200+p)*16+sg)*512 + lane*8 + j], sg = s*4 + fh*2 + tp.
__global__ __launch_bounds__(256) void k_spec_direct(
    const float* __restrict__ U, const unsigned short* __restrict__ xTa,
    unsigned short* __restrict__ part2)
{
    const int ktB  = blockIdx.x;                 // 0..7
    const int tid  = threadIdx.x;
    const int wid  = tid >> 6;
    const int lane = tid & 63;
    const int h = lane >> 4, m = lane & 15;
    const int nh = wid >> 1, fh = wid & 1;
    const int wsplit = blockIdx.y * 2 + nh;      // 0..199
    const int nt0 = wsplit * 8;                  // 8 nt-steps of 32n

    f32x4 acc[4][4];
    #pragma unroll
    for (int s = 0; s < 4; ++s)
        #pragma unroll
        for (int t = 0; t < 4; ++t)
            #pragma unroll
            for (int e = 0; e < 4; ++e) acc[s][t][e] = 0.f;

    const unsigned short* Bl = xTa + (size_t)lane * 8;
    const int ftb = fh * 4;
    const size_t colbase = (size_t)(ktB * 64 + m);

    for (int step = 0; step < 8; ++step) {
        const int nt = nt0 + step;
        const int nb = nt * 32 + 8 * h;

        bf16x8 a[4];
        #pragma unroll
        for (int s = 0; s < 4; ++s) {
            #pragma unroll
            for (int j = 0; j < 8; ++j) {
                int row = nb + j;
                int rc  = (row < N_NODES) ? row : (N_NODES - 1);
                float t = U[(size_t)rc * K_EIG + colbase + 16 * s];
                a[s][j] = (row < N_NODES) ? f2bf(t) : (short)0;
            }
        }
        bf16x8 b[4];
        #pragma unroll
        for (int t = 0; t < 4; ++t)
            b[t] = *reinterpret_cast<const bf16x8*>(
                Bl + ((size_t)(ftb + t) * NT32 + nt) * 512);

        #pragma unroll
        for (int s = 0; s < 4; ++s)
            #pragma unroll
            for (int t = 0; t < 4; ++t)
                acc[s][t] = __builtin_amdgcn_mfma_f32_16x16x32_bf16(
                    a[s], b[t], acc[s][t], 0, 0, 0);
    }

    // epilogue: 8x 16B fragment stores per lane (1KB/wave per slot)
    unsigned short* pb = part2 + ((size_t)(ktB * NWSPL + wsplit) * 16) * 512 + lane * 8;
    #pragma unroll
    for (int s = 0; s < 4; ++s)
        #pragma unroll
        for (int tp = 0; tp < 2; ++tp) {
            int sg = s * 4 + fh * 2 + tp;
            bf16x8 v;
            #pragma unroll
            for (int e = 0; e < 4; ++e) {
                v[e]     = f2bf(acc[s][2 * tp][e]);
                v[e + 4] = f2bf(acc[s][2 * tp + 1][e]);
            }
            *reinterpret_cast<bf16x8*>(pb + (size_t)sg * 512) = v;
        }
}

// ---------------- reduce stage 1: 200 -> 8 -----------------------------------
__global__ __launch_bounds__(256) void k_reduce1(
    const unsigned short* __restrict__ part2, float* __restrict__ part3)
{
    const int q  = blockIdx.x * 256 + threadIdx.x;   // 0..16383
    const int pg = blockIdx.y;                       // 0..7
    const int kt   = q >> 11;
    const int idx4 = q & 2047;
    const int sg   = idx4 >> 7;
    const int lane = (idx4 >> 1) & 63;
    const int e4   = (idx4 & 1) * 4;
    f32x4 s; s[0] = s[1] = s[2] = s[3] = 0.f;
    const int pend = pg * 25 + 25;
    for (int p = pg * 25; p < pend; ++p) {
        s16x4 v = *reinterpret_cast<const s16x4*>(
            part2 + ((size_t)(kt * NWSPL + p) * 16 + sg) * 512 + lane * 8 + e4);
        s[0] += bf2f((unsigned short)v[0]); s[1] += bf2f((unsigned short)v[1]);
        s[2] += bf2f((unsigned short)v[2]); s[3] += bf2f((unsigned short)v[3]);
    }
    *reinterpret_cast<f32x4*>(part3 + ((size_t)pg * 16384 + q) * 4) = s;
}

// ---------------- reduce stage 2: 8 -> 1, fold g, emit specbfa ---------------
// specbfa[ft16(8)][kt32(16)][l=16h'+m'][j'] = spec[ft*16+m'][kt32*32+8h'+j']
__global__ __launch_bounds__(256) void k_reduce2(
    const float* __restrict__ part3, const float* __restrict__ g,
    unsigned short* __restrict__ specbfa)
{
    const int q = blockIdx.x * 256 + threadIdx.x;    // 0..16383
    f32x4 s; s[0] = s[1] = s[2] = s[3] = 0.f;
    #pragma unroll
    for (int pg = 0; pg < 8; ++pg) {
        f32x4 v = *reinterpret_cast<const f32x4*>(part3 + ((size_t)pg * 16384 + q) * 4);
        s[0] += v[0]; s[1] += v[1]; s[2] += v[2]; s[3] += v[3];
    }
    const int kt   = q >> 11;
    const int idx4 = q & 2047;
    const int sg   = idx4 >> 7;
    const int lane = (idx4 >> 1) & 63;
    const int e4   = (idx4 & 1) * 4;
    const int h = lane >> 4, m = lane & 15;
    const int ss = sg >> 2, u = sg & 3;
    const int fh = u >> 1, tp = u & 1;
    const int jt = 2 * tp + (e4 >> 2);     // wave-local t of this elem group
    const int f  = (fh * 4 + jt) * 16 + m;
    const int kb = kt * 64 + 16 * ss + 4 * h;

    f32x4 gv = *reinterpret_cast<const f32x4*>(g + kb);
    s16x4 o;
    #pragma unroll
    for (int e = 0; e < 4; ++e) o[e] = f2bf(s[e] * gv[e]);
    size_t ad = ((size_t)((f >> 4) * 16 + (kb >> 5)) * 64
                 + ((kb >> 3) & 3) * 16 + (f & 15)) * 8 + (kb & 7);
    *reinterpret_cast<s16x4*>(specbfa + ad) = o;
}

// ---------------- GEMM2: A from f32 U (row-major), B frags, relu -------------
// 64n x 128f per block, 782 blocks; wave = 32n x 64f; reg double-buffered.
__global__ __launch_bounds__(256) void k_out_f32(
    const float* __restrict__ U, const unsigned short* __restrict__ specbfa,
    float* __restrict__ out)
{
    const int tid  = threadIdx.x;
    const int wid  = tid >> 6;
    const int lane = tid & 63;
    const int h = lane >> 4, m = lane & 15;
    const int wr = wid >> 1, wc = wid & 1;
    const int nbase = blockIdx.x * 64 + wr * 32;
    const int fbase = wc * 64;

    const float* Arow[2];
    #pragma unroll
    for (int i = 0; i < 2; ++i) {
        int n  = nbase + 16 * i + m;
        int nc = (n < N_NODES) ? n : (N_NODES - 1);
        Arow[i] = U + (size_t)nc * K_EIG + 8 * h;
    }
    const unsigned short* Blp[4];
    #pragma unroll
    for (int t = 0; t < 4; ++t)
        Blp[t] = specbfa + ((size_t)(4 * wc + t) * 8192 + lane * 8);

    f32x4 acc[2][4];
    #pragma unroll
    for (int i = 0; i < 2; ++i)
        #pragma unroll
        for (int t = 0; t < 4; ++t)
            #pragma unroll
            for (int e = 0; e < 4; ++e) acc[i][t][e] = 0.f;

    f32x4 loC[2], hiC[2]; bf16x8 bC[4];
    #pragma unroll
    for (int i = 0; i < 2; ++i) {
        loC[i] = *reinterpret_cast<const f32x4*>(Arow[i]);
        hiC[i] = *reinterpret_cast<const f32x4*>(Arow[i] + 4);
    }
    #pragma unroll
    for (int t = 0; t < 4; ++t)
        bC[t] = *reinterpret_cast<const bf16x8*>(Blp[t]);

    for (int kb = 0; kb < 16; ++kb) {            // kt32 steps of 32 k
        int kn = (kb + 1 < 16) ? kb + 1 : 0;     // clamp; last load unused
        f32x4 loN[2], hiN[2]; bf16x8 bN[4];
        #pragma unroll
        for (int i = 0; i < 2; ++i) {
            loN[i] = *reinterpret_cast<const f32x4*>(Arow[i] + kn * 32);
            hiN[i] = *reinterpret_cast<const f32x4*>(Arow[i] + kn * 32 + 4);
        }
        #pragma unroll
        for (int t = 0; t < 4; ++t)
            bN[t] = *reinterpret_cast<const bf16x8*>(Blp[t] + (size_t)kn * 512);

        bf16x8 a[2];
        #pragma unroll
        for (int i = 0; i < 2; ++i)
            #pragma unroll
            for (int j = 0; j < 4; ++j) {
                a[i][j]     = f2bf(loC[i][j]);
                a[i][j + 4] = f2bf(hiC[i][j]);
            }
        #pragma unroll
        for (int i = 0; i < 2; ++i)
            #pragma unroll
            for (int t = 0; t < 4; ++t)
                acc[i][t] = __builtin_amdgcn_mfma_f32_16x16x32_bf16(
                    a[i], bC[t], acc[i][t], 0, 0, 0);

        #pragma unroll
        for (int i = 0; i < 2; ++i) { loC[i] = loN[i]; hiC[i] = hiN[i]; }
        #pragma unroll
        for (int t = 0; t < 4; ++t) bC[t] = bN[t];
    }

    #pragma unroll
    for (int i = 0; i < 2; ++i)
        #pragma unroll
        for (int r = 0; r < 4; ++r) {
            int nn = nbase + 16 * i + 4 * h + r;
            if (nn < N_NODES) {
                float* orow = out + (long)nn * F_DIM + fbase + m;
                #pragma unroll
                for (int t = 0; t < 4; ++t)
                    orow[16 * t] = fmaxf(acc[i][t][r], 0.f);
            }
        }
}

// =================== deep fallback (round-1) if ws tiny ======================
__global__ __launch_bounds__(256) void k_spec_v1(
    const float* __restrict__ U, const float* __restrict__ g,
    const float* __restrict__ x, float* __restrict__ specT)
{
    const int kt    = blockIdx.x;
    const int split = blockIdx.y;
    const int tid   = threadIdx.x;
    const int wid   = tid >> 6;
    const int lane  = tid & 63;
    const int h     = lane >> 4;
    const int m     = lane & 15;
    const int k0 = kt * 64;
    const int f0 = wid * 32;
    const int chunk1 = 782;
    const int n_start = split * chunk1;
    int n_end = n_start + chunk1;
    if (n_end > N_NODES) n_end = N_NODES;

    f32x4 acc[4][2];
    #pragma unroll
    for (int s = 0; s < 4; ++s)
        #pragma unroll
        for (int t = 0; t < 2; ++t)
            #pragma unroll
            for (int e = 0; e < 4; ++e) acc[s][t][e] = 0.f;

    for (int nb = n_start; nb < n_end; nb += 32) {
        bf16x8 a[4]; bf16x8 b[2];
        const int nrow = nb + 8 * h;
        #pragma unroll
        for (int j = 0; j < 8; ++j) {
            int nn = nrow + j;
            bool valid = (nn < n_end);
            int nc = valid ? nn : (n_end - 1);
            const float* Urow = U + (long)nc * K_EIG + k0 + m;
            const float* Xrow = x + (long)nc * F_DIM + f0 + m;
            #pragma unroll
            for (int s = 0; s < 4; ++s) {
                short bv = f2bf(Urow[16 * s]);
                a[s][j] = valid ? bv : (short)0;
            }
            #pragma unroll
            for (int t = 0; t < 2; ++t) {
                short bv = f2bf(Xrow[16 * t]);
                b[t][j] = valid ? bv : (short)0;
            }
        }
        #pragma unroll
        for (int s = 0; s < 4; ++s)
            #pragma unroll
            for (int t = 0; t < 2; ++t)
                acc[s][t] = __builtin_amdgcn_mfma_f32_16x16x32_bf16(
                    a[s], b[t], acc[s][t], 0, 0, 0);
    }
    #pragma unroll
    for (int s = 0; s < 4; ++s)
        #pragma unroll
        for (int t = 0; t < 2; ++t)
            #pragma unroll
            for (int r = 0; r < 4; ++r) {
                int k = k0 + 16 * s + 4 * h + r;
                int f = f0 + 16 * t + m;
                atomicAdd(&specT[(long)f * K_EIG + k], acc[s][t][r] * g[k]);
            }
}

__global__ __launch_bounds__(256) void k_out_v1(
    const float* __restrict__ U, const float* __restrict__ specT,
    float* __restrict__ out)
{
    const int tid  = threadIdx.x;
    const int wid  = tid >> 6;
    const int lane = tid & 63;
    const int h = lane >> 4, m = lane & 15;
    const int wr = wid >> 1, wc = wid & 1;
    const int nbase = blockIdx.x * 128 + wr * 64;
    const int fbase = wc * 64;

    f32x4 acc[4][4];
    #pragma unroll
    for (int i = 0; i < 4; ++i)
        #pragma unroll
        for (int t = 0; t < 4; ++t)
            #pragma unroll
            for (int e = 0; e < 4; ++e) acc[i][t][e] = 0.f;

    for (int kb = 0; kb < K_EIG; kb += 32) {
        bf16x8 a[4], b[4];
        #pragma unroll
        for (int i = 0; i < 4; ++i) {
            int nn = nbase + 16 * i + m;
            bool valid = (nn < N_NODES);
            int nc = valid ? nn : (N_NODES - 1);
            const f32x4* p = reinterpret_cast<const f32x4*>(
                U + (long)nc * K_EIG + kb + 8 * h);
            f32x4 lo = p[0], hi = p[1];
            #pragma unroll
            for (int j = 0; j < 4; ++j) {
                short b0 = f2bf(lo[j]), b1 = f2bf(hi[j]);
                a[i][j]     = valid ? b0 : (short)0;
                a[i][j + 4] = valid ? b1 : (short)0;
            }
        }
        #pragma unroll
        for (int t = 0; t < 4; ++t) {
            const f32x4* p = reinterpret_cast<const f32x4*>(
                specT + (long)(fbase + 16 * t + m) * K_EIG + kb + 8 * h);
            f32x4 lo = p[0], hi = p[1];
            #pragma unroll
            for (int j = 0; j < 4; ++j) {
                b[t][j]     = f2bf(lo[j]);
                b[t][j + 4] = f2bf(hi[j]);
            }
        }
        #pragma unroll
        for (int i = 0; i < 4; ++i)
            #pragma unroll
            for (int t = 0; t < 4; ++t)
                acc[i][t] = __builtin_amdgcn_mfma_f32_16x16x32_bf16(
                    a[i], b[t], acc[i][t], 0, 0, 0);
    }
    #pragma unroll
    for (int i = 0; i < 4; ++i)
        #pragma unroll
        for (int r = 0; r < 4; ++r) {
            int nn = nbase + 16 * i + 4 * h + r;
            if (nn < N_NODES) {
                float* orow = out + (long)nn * F_DIM + fbase + m;
                #pragma unroll
                for (int t = 0; t < 4; ++t)
                    orow[16 * t] = fmaxf(acc[i][t][r], 0.f);
            }
        }
}

// ============================================================================
extern "C" void kernel_launch(void* const* d_in, const int* in_sizes, int n_in,
                              void* d_out, int out_size, void* d_ws, size_t ws_size,
                              hipStream_t stream) {
    const float* U = (const float*)d_in[0];
    const float* g = (const float*)d_in[1];
    const float* x = (const float*)d_in[2];
    float* out = (float*)d_out;

    // ws layout (bytes)
    const size_t OFF_XTA   = 0;                 // 8*1600*512*2   = 13,107,200
    const size_t OFF_PART2 = 13107200;          // 8*200*16*512*2 = 26,214,400
    const size_t OFF_PART3 = 39321600;          // 8*16384*4*4    =  2,097,152
    const size_t OFF_SPECA = 41418752;          // 8*16*512*2     =    131,072
    const size_t WS_NEEDED = 41549824;

    if (ws_size >= WS_NEEDED) {
        unsigned short* xTa     = (unsigned short*)((char*)d_ws + OFF_XTA);
        unsigned short* part2   = (unsigned short*)((char*)d_ws + OFF_PART2);
        float*          part3   = (float*)((char*)d_ws + OFF_PART3);
        unsigned short* specbfa = (unsigned short*)((char*)d_ws + OFF_SPECA);

        dim3 gx(NPAD / 64, F_DIM / 64);   // 800 x 2
        prep_x<<<gx, 256, 0, stream>>>(x, xTa);

        dim3 g1(K_EIG / 64, NWSPL / 2);   // 8 x 100 = 800 blocks
        k_spec_direct<<<g1, 256, 0, stream>>>(U, xTa, part2);

        dim3 gr1(64, 8);                  // 512 blocks
        k_reduce1<<<gr1, 256, 0, stream>>>(part2, part3);
        k_reduce2<<<64, 256, 0, stream>>>(part3, g, specbfa);

        int nb2 = (N_NODES + 63) / 64;    // 782
        k_out_f32<<<nb2, 256, 0, stream>>>(U, specbfa, out);
    } else {
        float* specT = (float*)d_ws;      // 256 KB
        hipMemsetAsync(specT, 0, (size_t)K_EIG * F_DIM * sizeof(float), stream);
        dim3 g1(K_EIG / 64, 64);
        k_spec_v1<<<g1, 256, 0, stream>>>(U, g, x, specT);
        int nb2 = (N_NODES + 127) / 128;
        k_out_v1<<<nb2, 256, 0, stream>>>(U, specT, out);
    }
}

// Round 15
// 96.861 us; speedup vs baseline: 1.9455x; 1.9455x over previous
//
#include <hip/hip_runtime.h>
#include <hip/hip_bf16.h>

#define N_NODES 50000
#define K_EIG   512
#define F_DIM   128
#define NPAD    51200     // 200 splits * 256
#define NSPLITS 200
#define CHUNK   256
#define NT32    1600      // NPAD/32

typedef __attribute__((ext_vector_type(8))) short bf16x8;
typedef __attribute__((ext_vector_type(4))) short s16x4;
typedef __attribute__((ext_vector_type(4))) float f32x4;
typedef __attribute__((ext_vector_type(2))) unsigned u32x2;

static __device__ __forceinline__ unsigned pk2(float lo, float hi) {
    unsigned short a = __builtin_bit_cast(unsigned short, __float2bfloat16(lo));
    unsigned short b = __builtin_bit_cast(unsigned short, __float2bfloat16(hi));
    return ((unsigned)b << 16) | (unsigned)a;
}

static __device__ __forceinline__ short f2bf(float f) {
    union { float f; unsigned u; } v; v.f = f;
    unsigned r = v.u + 0x7fffu + ((v.u >> 16) & 1u);   // RNE
    return (short)(r >> 16);
}

static __device__ __forceinline__ float bf2f(unsigned short u) {
    union { unsigned u; float f; } v; v.u = ((unsigned)u) << 16;
    return v.f;
}

// ---------------- prep: x -> xTa fragment-ready ------------------------------
// xTa[ft16(8)][nt32(1600)][lane(64)][8]: xTa[ft][nt][16h+m][j] = x[nt*32+8h+j][ft*16+m]
__global__ __launch_bounds__(256) void prep_x(const float* __restrict__ x,
                                              unsigned short* __restrict__ xTa)
{
    const int n0 = blockIdx.x * 64;
    const int f0 = blockIdx.y * 64;
    const int fa = threadIdx.x & 15;
    const int nb = threadIdx.x >> 4;
    const int n  = n0 + 4 * nb;
    const int f  = f0 + 4 * fa;

    float r[4][4];
    #pragma unroll
    for (int jj = 0; jj < 4; ++jj) {
        int nr = n + jj;
        if (nr < N_NODES) {
            f32x4 v = *reinterpret_cast<const f32x4*>(x + (long)nr * F_DIM + f);
            r[jj][0] = v[0]; r[jj][1] = v[1]; r[jj][2] = v[2]; r[jj][3] = v[3];
        } else {
            r[jj][0] = r[jj][1] = r[jj][2] = r[jj][3] = 0.f;
        }
    }
    const int nt32 = n >> 5;
    const int hpart = ((n >> 3) & 3) * 16;
    const int slot  = 4 * (nb & 1);
    #pragma unroll
    for (int i = 0; i < 4; ++i) {
        int fi = f + i;
        size_t ad = ((size_t)((fi >> 4) * NT32 + nt32) * 64 + hpart + (fi & 15)) * 8 + slot;
        u32x2 w; w[0] = pk2(r[0][i], r[1][i]); w[1] = pk2(r[2][i], r[3][i]);
        *reinterpret_cast<u32x2*>(xTa + ad) = w;
    }
}

// ---------------- fused GEMM1: LDS-transpose of U + MFMA (no Ubfa) -----------
// part2[kt][split][tid][32] = per-thread acc fragments (bf16).
// grid (split=200, kt=8): linear id = split + 200*kt; XCD = id%8 = split%8, so
// the 8 kt-blocks sharing one U-tile land on the SAME XCD -> L2-served re-reads.
__global__ __launch_bounds__(256) void k_spec_f(
    const float* __restrict__ U, const unsigned short* __restrict__ xTa,
    unsigned short* __restrict__ part2)
{
    __shared__ unsigned char lds1[2][64 * 128];   // 16 KB, double-buffered

    const int split = blockIdx.x;      // 0..199
    const int kt    = blockIdx.y;      // 0..7
    const int tid   = threadIdx.x;
    const int wid   = tid >> 6;
    const int lane  = tid & 63;
    const int h     = lane >> 4;
    const int m     = lane & 15;
    const int k0    = kt * 64;
    const int nbeg  = split * CHUNK;

    const int kq = tid & 15;    // k-quad (coalesced U reads)
    const int nq = tid >> 4;    // n-quad

    f32x4 acc[4][2];
    #pragma unroll
    for (int s = 0; s < 4; ++s)
        #pragma unroll
        for (int t = 0; t < 2; ++t)
            #pragma unroll
            for (int e = 0; e < 4; ++e) acc[s][t][e] = 0.f;

    const unsigned short* Bl = xTa + (size_t)lane * 8;
    const int ftb = wid * 2;   // ft16 base for this wave (f0 = wid*32)

    float  r[4][4];
    bf16x8 bfr[2][2];

    // ---- prologue: step-0 U tile + B frags ----
    #pragma unroll
    for (int j = 0; j < 4; ++j) {
        int n = nbeg + 4 * nq + j;
        if (n < N_NODES) {
            f32x4 v = *reinterpret_cast<const f32x4*>(U + (long)n * K_EIG + k0 + 4 * kq);
            r[j][0] = v[0]; r[j][1] = v[1]; r[j][2] = v[2]; r[j][3] = v[3];
        } else {
            r[j][0] = r[j][1] = r[j][2] = r[j][3] = 0.f;
        }
    }
    #pragma unroll
    for (int sub = 0; sub < 2; ++sub)
        #pragma unroll
        for (int t = 0; t < 2; ++t)
            bfr[sub][t] = *reinterpret_cast<const bf16x8*>(
                Bl + (size_t)((ftb + t) * NT32 + (nbeg >> 5) + sub) * 512);

    #pragma unroll
    for (int step = 0; step < 4; ++step) {
        const int ntile = nbeg + 64 * step;
        const int buf   = step & 1;

        // ---- prefetch next step ----
        float  rN[4][4];
        bf16x8 bN[2][2];
        if (step < 3) {
            const int nt2 = ntile + 64;
            #pragma unroll
            for (int j = 0; j < 4; ++j) {
                int n = nt2 + 4 * nq + j;
                if (n < N_NODES) {
                    f32x4 v = *reinterpret_cast<const f32x4*>(
                        U + (long)n * K_EIG + k0 + 4 * kq);
                    rN[j][0] = v[0]; rN[j][1] = v[1]; rN[j][2] = v[2]; rN[j][3] = v[3];
                } else {
                    rN[j][0] = rN[j][1] = rN[j][2] = rN[j][3] = 0.f;
                }
            }
            #pragma unroll
            for (int sub = 0; sub < 2; ++sub)
                #pragma unroll
                for (int t = 0; t < 2; ++t)
                    bN[sub][t] = *reinterpret_cast<const bf16x8*>(
                        Bl + (size_t)((ftb + t) * NT32 + (nt2 >> 5) + sub) * 512);
        }

        // ---- LDS1: transpose [k][n], byte ^= (k&7)<<4 ----
        #pragma unroll
        for (int i = 0; i < 4; ++i) {
            int kl = 4 * kq + i;
            unsigned lo = pk2(r[0][i], r[1][i]);
            unsigned hi = pk2(r[2][i], r[3][i]);
            int byte = (kl * 128 + 8 * nq) ^ ((kl & 7) << 4);
            *reinterpret_cast<unsigned long long*>(&lds1[buf][byte]) =
                ((unsigned long long)hi << 32) | (unsigned long long)lo;
        }
        __syncthreads();

        // ---- MFMA: A frags from LDS1 ----
        #pragma unroll
        for (int sub = 0; sub < 2; ++sub) {
            bf16x8 af[4];
            #pragma unroll
            for (int s = 0; s < 4; ++s) {
                int row  = 16 * s + m;
                int byte = (row * 128 + 64 * sub + 16 * h) ^ ((m & 7) << 4);
                af[s] = *reinterpret_cast<const bf16x8*>(&lds1[buf][byte]);
            }
            #pragma unroll
            for (int s = 0; s < 4; ++s)
                #pragma unroll
                for (int t = 0; t < 2; ++t)
                    acc[s][t] = __builtin_amdgcn_mfma_f32_16x16x32_bf16(
                        af[s], bfr[sub][t], acc[s][t], 0, 0, 0);
        }

        // ---- rotate ----
        if (step < 3) {
            #pragma unroll
            for (int j = 0; j < 4; ++j)
                #pragma unroll
                for (int i = 0; i < 4; ++i) r[j][i] = rN[j][i];
            #pragma unroll
            for (int sub = 0; sub < 2; ++sub)
                #pragma unroll
                for (int t = 0; t < 2; ++t) bfr[sub][t] = bN[sub][t];
        }
    }

    // ---- epilogue: flat per-thread fragment store (coalesced) ----
    unsigned short* pb = part2 + (((size_t)(kt * NSPLITS + split)) * 256 + tid) * 32;
    #pragma unroll
    for (int s = 0; s < 4; ++s) {
        bf16x8 v;
        #pragma unroll
        for (int e = 0; e < 4; ++e) {
            v[e]     = f2bf(acc[s][0][e]);
            v[e + 4] = f2bf(acc[s][1][e]);
        }
        *reinterpret_cast<bf16x8*>(pb + s * 8) = v;
    }
}

// ---------------- reduce stage 1: 200 -> 8 (coalesced reads) -----------------
__global__ __launch_bounds__(256) void k_reduce1(
    const unsigned short* __restrict__ part2, float* __restrict__ part3)
{
    const int q  = blockIdx.x * 256 + threadIdx.x;   // 0..16383
    const int pg = blockIdx.y;                       // 0..7
    const int kt = q >> 11;
    const int tp = (q >> 3) & 255;
    const int sl = q & 7;
    f32x4 s; s[0] = s[1] = s[2] = s[3] = 0.f;
    const int pend = pg * 25 + 25;
    for (int p = pg * 25; p < pend; ++p) {
        s16x4 v = *reinterpret_cast<const s16x4*>(
            part2 + (((size_t)(kt * NSPLITS + p)) * 256 + tp) * 32 + sl * 4);
        s[0] += bf2f((unsigned short)v[0]); s[1] += bf2f((unsigned short)v[1]);
        s[2] += bf2f((unsigned short)v[2]); s[3] += bf2f((unsigned short)v[3]);
    }
    *reinterpret_cast<f32x4*>(part3 + ((size_t)pg * 16384 + q) * 4) = s;
}

// ---------------- reduce stage 2: 8 -> 1, fold g, emit specbfa ---------------
// specbfa[ft16(8)][kt32(16)][lane][8]: [ft][kt][16h+m][j] = spec[ft*16+m][kt*32+8h+j]
__global__ __launch_bounds__(256) void k_reduce2(
    const float* __restrict__ part3, const float* __restrict__ g,
    unsigned short* __restrict__ specbfa)
{
    const int q = blockIdx.x * 256 + threadIdx.x;    // 0..16383
    f32x4 s; s[0] = s[1] = s[2] = s[3] = 0.f;
    #pragma unroll
    for (int pg = 0; pg < 8; ++pg) {
        f32x4 v = *reinterpret_cast<const f32x4*>(part3 + ((size_t)pg * 16384 + q) * 4);
        s[0] += v[0]; s[1] += v[1]; s[2] += v[2]; s[3] += v[3];
    }
    const int kt = q >> 11, tp = (q >> 3) & 255, sl = q & 7;
    const int wid = tp >> 6, le = tp & 63, hh = le >> 4, mm = le & 15;
    const int ss = sl >> 1, tt = sl & 1;
    const int f = wid * 32 + tt * 16 + mm;
    const int k = kt * 64 + ss * 16 + hh * 4;
    f32x4 gv = *reinterpret_cast<const f32x4*>(g + k);
    s16x4 o;
    #pragma unroll
    for (int e = 0; e < 4; ++e) o[e] = f2bf(s[e] * gv[e]);
    const int lanep = ((k >> 3) & 3) * 16 + (f & 15);
    size_t ad = ((size_t)((f >> 4) * 16 + (k >> 5)) * 64 + lanep) * 8 + (k & 7);
    *reinterpret_cast<s16x4*>(specbfa + ad) = o;
}

// ---------------- GEMM2: A from f32 U (row-major, L3-hot), B frags, relu -----
// 64n x 128f per block, 782 blocks; wave = 32n x 64f; reg double-buffered.
__global__ __launch_bounds__(256) void k_out_f32(
    const float* __restrict__ U, const unsigned short* __restrict__ specbfa,
    float* __restrict__ out)
{
    const int tid  = threadIdx.x;
    const int wid  = tid >> 6;
    const int lane = tid & 63;
    const int h = lane >> 4, m = lane & 15;
    const int wr = wid >> 1, wc = wid & 1;
    const int nbase = blockIdx.x * 64 + wr * 32;
    const int fbase = wc * 64;

    const float* Arow[2];
    #pragma unroll
    for (int i = 0; i < 2; ++i) {
        int n  = nbase + 16 * i + m;
        int nc = (n < N_NODES) ? n : (N_NODES - 1);
        Arow[i] = U + (size_t)nc * K_EIG + 8 * h;
    }
    const unsigned short* Blp[4];
    #pragma unroll
    for (int t = 0; t < 4; ++t)
        Blp[t] = specbfa + ((size_t)(4 * wc + t) * 8192 + lane * 8);

    f32x4 acc[2][4];
    #pragma unroll
    for (int i = 0; i < 2; ++i)
        #pragma unroll
        for (int t = 0; t < 4; ++t)
            #pragma unroll
            for (int e = 0; e < 4; ++e) acc[i][t][e] = 0.f;

    f32x4 loC[2], hiC[2]; bf16x8 bC[4];
    #pragma unroll
    for (int i = 0; i < 2; ++i) {
        loC[i] = *reinterpret_cast<const f32x4*>(Arow[i]);
        hiC[i] = *reinterpret_cast<const f32x4*>(Arow[i] + 4);
    }
    #pragma unroll
    for (int t = 0; t < 4; ++t)
        bC[t] = *reinterpret_cast<const bf16x8*>(Blp[t]);

    for (int kb = 0; kb < 16; ++kb) {            // kt32 steps of 32 k
        int kn = (kb + 1 < 16) ? kb + 1 : 0;     // clamp; last load unused
        f32x4 loN[2], hiN[2]; bf16x8 bN[4];
        #pragma unroll
        for (int i = 0; i < 2; ++i) {
            loN[i] = *reinterpret_cast<const f32x4*>(Arow[i] + kn * 32);
            hiN[i] = *reinterpret_cast<const f32x4*>(Arow[i] + kn * 32 + 4);
        }
        #pragma unroll
        for (int t = 0; t < 4; ++t)
            bN[t] = *reinterpret_cast<const bf16x8*>(Blp[t] + (size_t)kn * 512);

        bf16x8 a[2];
        #pragma unroll
        for (int i = 0; i < 2; ++i)
            #pragma unroll
            for (int j = 0; j < 4; ++j) {
                a[i][j]     = f2bf(loC[i][j]);
                a[i][j + 4] = f2bf(hiC[i][j]);
            }
        #pragma unroll
        for (int i = 0; i < 2; ++i)
            #pragma unroll
            for (int t = 0; t < 4; ++t)
                acc[i][t] = __builtin_amdgcn_mfma_f32_16x16x32_bf16(
                    a[i], bC[t], acc[i][t], 0, 0, 0);

        #pragma unroll
        for (int i = 0; i < 2; ++i) { loC[i] = loN[i]; hiC[i] = hiN[i]; }
        #pragma unroll
        for (int t = 0; t < 4; ++t) bC[t] = bN[t];
    }

    #pragma unroll
    for (int i = 0; i < 2; ++i)
        #pragma unroll
        for (int r = 0; r < 4; ++r) {
            int nn = nbase + 16 * i + 4 * h + r;
            if (nn < N_NODES) {
                float* orow = out + (long)nn * F_DIM + fbase + m;
                #pragma unroll
                for (int t = 0; t < 4; ++t)
                    orow[16 * t] = fmaxf(acc[i][t][r], 0.f);
            }
        }
}

// =================== deep fallback (round-1) if ws tiny ======================
__global__ __launch_bounds__(256) void k_spec_v1(
    const float* __restrict__ U, const float* __restrict__ g,
    const float* __restrict__ x, float* __restrict__ specT)
{
    const int kt    = blockIdx.x;
    const int split = blockIdx.y;
    const int tid   = threadIdx.x;
    const int wid   = tid >> 6;
    const int lane  = tid & 63;
    const int h     = lane >> 4;
    const int m     = lane & 15;
    const int k0 = kt * 64;
    const int f0 = wid * 32;
    const int chunk1 = 782;
    const int n_start = split * chunk1;
    int n_end = n_start + chunk1;
    if (n_end > N_NODES) n_end = N_NODES;

    f32x4 acc[4][2];
    #pragma unroll
    for (int s = 0; s < 4; ++s)
        #pragma unroll
        for (int t = 0; t < 2; ++t)
            #pragma unroll
            for (int e = 0; e < 4; ++e) acc[s][t][e] = 0.f;

    for (int nb = n_start; nb < n_end; nb += 32) {
        bf16x8 a[4]; bf16x8 b[2];
        const int nrow = nb + 8 * h;
        #pragma unroll
        for (int j = 0; j < 8; ++j) {
            int nn = nrow + j;
            bool valid = (nn < n_end);
            int nc = valid ? nn : (n_end - 1);
            const float* Urow = U + (long)nc * K_EIG + k0 + m;
            const float* Xrow = x + (long)nc * F_DIM + f0 + m;
            #pragma unroll
            for (int s = 0; s < 4; ++s) {
                short bv = f2bf(Urow[16 * s]);
                a[s][j] = valid ? bv : (short)0;
            }
            #pragma unroll
            for (int t = 0; t < 2; ++t) {
                short bv = f2bf(Xrow[16 * t]);
                b[t][j] = valid ? bv : (short)0;
            }
        }
        #pragma unroll
        for (int s = 0; s < 4; ++s)
            #pragma unroll
            for (int t = 0; t < 2; ++t)
                acc[s][t] = __builtin_amdgcn_mfma_f32_16x16x32_bf16(
                    a[s], b[t], acc[s][t], 0, 0, 0);
    }
    #pragma unroll
    for (int s = 0; s < 4; ++s)
        #pragma unroll
        for (int t = 0; t < 2; ++t)
            #pragma unroll
            for (int r = 0; r < 4; ++r) {
                int k = k0 + 16 * s + 4 * h + r;
                int f = f0 + 16 * t + m;
                atomicAdd(&specT[(long)f * K_EIG + k], acc[s][t][r] * g[k]);
            }
}

__global__ __launch_bounds__(256) void k_out_v1(
    const float* __restrict__ U, const float* __restrict__ specT,
    float* __restrict__ out)
{
    const int tid  = threadIdx.x;
    const int wid  = tid >> 6;
    const int lane = tid & 63;
    const int h = lane >> 4, m = lane & 15;
    const int wr = wid >> 1, wc = wid & 1;
    const int nbase = blockIdx.x * 128 + wr * 64;
    const int fbase = wc * 64;

    f32x4 acc[4][4];
    #pragma unroll
    for (int i = 0; i < 4; ++i)
        #pragma unroll
        for (int t = 0; t < 4; ++t)
            #pragma unroll
            for (int e = 0; e < 4; ++e) acc[i][t][e] = 0.f;

    for (int kb = 0; kb < K_EIG; kb += 32) {
        bf16x8 a[4], b[4];
        #pragma unroll
        for (int i = 0; i < 4; ++i) {
            int nn = nbase + 16 * i + m;
            bool valid = (nn < N_NODES);
            int nc = valid ? nn : (N_NODES - 1);
            const f32x4* p = reinterpret_cast<const f32x4*>(
                U + (long)nc * K_EIG + kb + 8 * h);
            f32x4 lo = p[0], hi = p[1];
            #pragma unroll
            for (int j = 0; j < 4; ++j) {
                short b0 = f2bf(lo[j]), b1 = f2bf(hi[j]);
                a[i][j]     = valid ? b0 : (short)0;
                a[i][j + 4] = valid ? b1 : (short)0;
            }
        }
        #pragma unroll
        for (int t = 0; t < 4; ++t) {
            const f32x4* p = reinterpret_cast<const f32x4*>(
                specT + (long)(fbase + 16 * t + m) * K_EIG + kb + 8 * h);
            f32x4 lo = p[0], hi = p[1];
            #pragma unroll
            for (int j = 0; j < 4; ++j) {
                b[t][j]     = f2bf(lo[j]);
                b[t][j + 4] = f2bf(hi[j]);
            }
        }
        #pragma unroll
        for (int i = 0; i < 4; ++i)
            #pragma unroll
            for (int t = 0; t < 4; ++t)
                acc[i][t] = __builtin_amdgcn_mfma_f32_16x16x32_bf16(
                    a[i], b[t], acc[i][t], 0, 0, 0);
    }
    #pragma unroll
    for (int i = 0; i < 4; ++i)
        #pragma unroll
        for (int r = 0; r < 4; ++r) {
            int nn = nbase + 16 * i + 4 * h + r;
            if (nn < N_NODES) {
                float* orow = out + (long)nn * F_DIM + fbase + m;
                #pragma unroll
                for (int t = 0; t < 4; ++t)
                    orow[16 * t] = fmaxf(acc[i][t][r], 0.f);
            }
        }
}

// ============================================================================
extern "C" void kernel_launch(void* const* d_in, const int* in_sizes, int n_in,
                              void* d_out, int out_size, void* d_ws, size_t ws_size,
                              hipStream_t stream) {
    const float* U = (const float*)d_in[0];
    const float* g = (const float*)d_in[1];
    const float* x = (const float*)d_in[2];
    float* out = (float*)d_out;

    // ws layout (bytes)
    const size_t OFF_XTA   = 0;                 // 8*1600*512*2   = 13,107,200
    const size_t OFF_PART2 = 13107200;          // 8*200*256*32*2 = 26,214,400
    const size_t OFF_PART3 = 39321600;          // 8*16384*4*4    =  2,097,152
    const size_t OFF_SPECA = 41418752;          // 8*16*512*2     =    131,072
    const size_t WS_NEEDED = 41549824;

    if (ws_size >= WS_NEEDED) {
        unsigned short* xTa     = (unsigned short*)((char*)d_ws + OFF_XTA);
        unsigned short* part2   = (unsigned short*)((char*)d_ws + OFF_PART2);
        float*          part3   = (float*)((char*)d_ws + OFF_PART3);
        unsigned short* specbfa = (unsigned short*)((char*)d_ws + OFF_SPECA);

        dim3 gx(NPAD / 64, F_DIM / 64);   // 800 x 2
        prep_x<<<gx, 256, 0, stream>>>(x, xTa);

        // split-major grid: XCD = (split + 200*kt) % 8 = split % 8 --
        // all 8 kt-blocks of one U-tile share an XCD's L2.
        dim3 g1(NSPLITS, K_EIG / 64);     // 200 x 8 = 1600 blocks
        k_spec_f<<<g1, 256, 0, stream>>>(U, xTa, part2);

        dim3 gr1(64, 8);                  // 512 blocks
        k_reduce1<<<gr1, 256, 0, stream>>>(part2, part3);
        k_reduce2<<<64, 256, 0, stream>>>(part3, g, specbfa);

        int nb2 = (N_NODES + 63) / 64;    // 782
        k_out_f32<<<nb2, 256, 0, stream>>>(U, specbfa, out);
    } else {
        float* specT = (float*)d_ws;      // 256 KB
        hipMemsetAsync(specT, 0, (size_t)K_EIG * F_DIM * sizeof(float), stream);
        dim3 g1(K_EIG / 64, 64);
        k_spec_v1<<<g1, 256, 0, stream>>>(U, g, x, specT);
        int nb2 = (N_NODES + 127) / 128;
        k_out_v1<<<nb2, 256, 0, stream>>>(U, specT, out);
    }
}